// Round 23
// baseline (1119.619 us; speedup 1.0000x reference)
//
#include <hip/hip_runtime.h>
#include <hip/hip_fp16.h>

#define NN 50000
#define TT 12
#define EE 800000
#define IN_C 32
#define HID 64
#define OUT_C 32
#define NBLK2 ((NN + 255) / 256)      // 196 scan blocks
#define EBLK3 ((EE + 255) / 256)      // 3125 edge blocks
#define GBLK4 ((NN + 63) / 64)        // 782 gate blocks (tail handled by guards)
#define GT 4                          // timesteps per gate block
#define WFIX 262144.0f                // 2^18 fixed-point for weight sums
#define XPAIRS ((size_t)TT * NN * 16) // half2 elements in x

typedef _Float16 half8_t __attribute__((ext_vector_type(8)));
typedef float f32x4_t __attribute__((ext_vector_type(4)));

// ---------------- precompute folded gate matrices ----------------
// Mz = Wz @ Lz_w[:64] (32x64), Bz = bz @ Lz_w[:64] + Lz_b (64); same for h.
__global__ __launch_bounds__(64) void prep_kernel(
    const float* __restrict__ Wz, const float* __restrict__ bz,
    const float* __restrict__ Lzw, const float* __restrict__ Lzb,
    const float* __restrict__ Wh, const float* __restrict__ bh,
    const float* __restrict__ Lhw, const float* __restrict__ Lhb,
    float* __restrict__ Mz, float* __restrict__ Bz,
    float* __restrict__ Mh, float* __restrict__ Bh) {
  const int j = threadIdx.x;
  const int i = blockIdx.x;
  const int h = blockIdx.y;
  const float* W  = h ? Wh  : Wz;
  const float* b  = h ? bh  : bz;
  const float* L  = h ? Lhw : Lzw;
  const float* Lb = h ? Lhb : Lzb;
  float* M = h ? Mh : Mz;
  float* B = h ? Bh : Bz;
  if (i < IN_C) {
    float v = 0.f;
    for (int k = 0; k < HID; ++k) v += W[i * HID + k] * L[k * HID + j];
    M[i * HID + j] = v;
  } else {
    float v = Lb[j];
    for (int k = 0; k < HID; ++k) v += b[k] * L[k * HID + j];
    B[j] = v;
  }
}

// pack M into MFMA B-operand fp16 layout: B16[(g*4+cc)*64 + lane][i] =
// M_g[k = 8*(lane>>4)+i][col = cc*16 + (lane&15)]
__global__ __launch_bounds__(64) void prep_b16_kernel(
    const float* __restrict__ Mz, const float* __restrict__ Mh,
    _Float16* __restrict__ B16) {
  int l = threadIdx.x;
  int cc = blockIdx.x;  // coltile 0..3
  int g = blockIdx.y;   // 0=z, 1=h
  const float* M = g ? Mh : Mz;
#pragma unroll
  for (int i = 0; i < 8; ++i) {
    int k = (l >> 4) * 8 + i;
    int col = cc * 16 + (l & 15);
    B16[(((size_t)g * 4 + cc) * 64 + l) * 8 + i] = (_Float16)M[k * HID + col];
  }
}

// x [T,N,32] fp32 -> fp16 pairs
__global__ __launch_bounds__(256) void xconv_kernel(const float* __restrict__ x,
                                                    __half2* __restrict__ xh) {
  size_t i = (size_t)blockIdx.x * 256 + threadIdx.x;
  if (i < XPAIRS) {
    float2 f = ((const float2*)x)[i];
    xh[i] = __floats2half2_rn(f.x, f.y);
  }
}

// hist: one packed u32 atomic per edge: {count<<24 | round(w*2^18)}.
// count <= ~50 (Poisson(16)), wsum < 50*2^18 < 2^24 -> no carry (R4 trick).
__global__ __launch_bounds__(256) void hist_kernel(const int* __restrict__ ei,
                                                   const float* __restrict__ ew,
                                                   unsigned* __restrict__ pcA,
                                                   int tbase) {
  int tl = blockIdx.y;
  const int* dst = ei + (size_t)(tbase + tl) * 2 * EE + EE;
  const float* w = ew + (size_t)(tbase + tl) * EE;
  unsigned* pc = pcA + (size_t)tl * NN;
  int e = blockIdx.x * 256 + threadIdx.x;
  if (e < EE) {
    unsigned wf = __float2uint_rn(w[e] * WFIX);
    atomicAdd(&pc[dst[e]], (1u << 24) + wf);
  }
}

// per-256-node-chunk count sums -> bsum (R3-proven structure)
__global__ __launch_bounds__(256) void partial_kernel(
    const unsigned* __restrict__ pcA, int* __restrict__ bsumA) {
  const unsigned* pc = pcA + (size_t)blockIdx.y * NN;
  int* bsum = bsumA + (size_t)blockIdx.y * NBLK2;
  __shared__ int s[256];
  int t = threadIdx.x;
  int idx = blockIdx.x * 256 + t;
  s[t] = (idx < NN) ? (int)(pc[idx] >> 24) : 0;
  __syncthreads();
  for (int o = 128; o > 0; o >>= 1) {
    if (t < o) s[t] += s[t + o];
    __syncthreads();
  }
  if (t == 0) bsum[blockIdx.x] = s[0];
}

// scan block partials for base + local scan; writes noff, cursor, and
// dinv = rsqrt(1 + wsum/2^18)  (R3-proven structure + dinv fold)
__global__ __launch_bounds__(256) void offs_kernel(
    const int* __restrict__ bsumA, const unsigned* __restrict__ pcA,
    int* __restrict__ cursorA, int* __restrict__ noffA, float* __restrict__ dinvA) {
  int tl = blockIdx.y;
  const int* bsum = bsumA + (size_t)tl * NBLK2;
  const unsigned* pc = pcA + (size_t)tl * NN;
  int* cursor = cursorA + (size_t)tl * NN;
  int* noff = noffA + (size_t)tl * (NN + 1);
  float* dinv = dinvA + (size_t)tl * NN;
  __shared__ int sb[256];
  __shared__ int sc[256];
  int b = blockIdx.x, t = threadIdx.x;
  sb[t] = (t < NBLK2) ? bsum[t] : 0;
  __syncthreads();
  for (int o = 1; o < 256; o <<= 1) {
    int v = (t >= o) ? sb[t - o] : 0;
    __syncthreads();
    sb[t] += v;
    __syncthreads();
  }
  int boff = (b == 0) ? 0 : sb[b - 1];
  int idx = b * 256 + t;
  unsigned p = (idx < NN) ? pc[idx] : 0u;
  int cv = (int)(p >> 24);
  sc[t] = cv;
  __syncthreads();
  for (int o = 1; o < 256; o <<= 1) {
    int v = (t >= o) ? sc[t - o] : 0;
    __syncthreads();
    sc[t] += v;
    __syncthreads();
  }
  if (idx < NN) {
    int o2 = boff + sc[t] - cv;  // exclusive
    noff[idx] = o2;
    cursor[idx] = o2;
    dinv[idx] = rsqrtf(1.0f + (float)(p & 0xFFFFFFu) * (1.0f / WFIX));
  }
  if (b == NBLK2 - 1 && t == 255) noff[NN] = boff + sc[t];  // == EE
}

// place (R2-R4's proven fill): direct CSR scatter. sbuf/t = 3.2 MB -> the
// ~5 live t-slices fit L2, so lines stay resident until full (the condition
// bin's 120 MB live set violated). Entry {src16 | fp16(w*dinv[src]) << 16}.
__global__ __launch_bounds__(256) void place_kernel(const int* __restrict__ ei,
                                                    const float* __restrict__ ew,
                                                    const float* __restrict__ dinvA,
                                                    int* __restrict__ cursorA,
                                                    unsigned* __restrict__ sbufG,
                                                    int tbase) {
  int tl = blockIdx.y;
  const int* src = ei + (size_t)(tbase + tl) * 2 * EE;
  const int* dst = src + EE;
  const float* w = ew + (size_t)(tbase + tl) * EE;
  const float* dinv = dinvA + (size_t)tl * NN;
  int* cursor = cursorA + (size_t)tl * NN;
  unsigned* sbuf = sbufG + (size_t)tl * EE;
  int e = blockIdx.x * 256 + threadIdx.x;
  if (e >= EE) return;
  int s = src[e], d = dst[e];
  float nm = w[e] * dinv[s];
  int pos = atomicAdd(&cursor[d], 1);
  sbuf[pos] = (unsigned)s | ((unsigned)__half_as_ushort(__float2half_rn(nm)) << 16);
}

// Pass B1: pure gather, NO LDS / NO barriers; t-major grid keeps xh_t
// L2-resident (proven R13/R21). lane = {node-half, 8 edge-groups, 4
// channel-octs}; per-edge uint4 row reads -> 16 row-loads in flight/wave.
__global__ __launch_bounds__(256) void gather_y_kernel(
    const float* __restrict__ x, const __half2* __restrict__ xh,
    const float* __restrict__ dinvA, const int* __restrict__ noffG,
    const unsigned* __restrict__ sbufG, __half2* __restrict__ yG, int tbase) {
  int t = threadIdx.x;
  int w = t >> 6;            // wave 0..3
  int lane = t & 63;
  int h2 = lane >> 5;        // node half 0/1
  int g = (lane >> 2) & 7;   // edge group 0..7
  int cq = lane & 3;         // channel oct 0..3 (8 fp16 ch = uint4)
  int tl = blockIdx.y;
  int n = blockIdx.x * 8 + w * 2 + h2;  // NN % 8 == 0, no tail

  const float* dinv = dinvA + (size_t)tl * NN;
  const int* noff = noffG + (size_t)tl * (NN + 1);
  const unsigned* sbuf = sbufG + (size_t)tl * EE;
  const __half2* xht = xh + (size_t)(tbase + tl) * NN * 16;
  const float* xt = x + (size_t)(tbase + tl) * NN * IN_C;

  int e0 = noff[n], e1 = noff[n + 1];
  float v0 = 0.f, v1 = 0.f, v2 = 0.f, v3 = 0.f;
  float v4 = 0.f, v5 = 0.f, v6 = 0.f, v7 = 0.f;
  for (int e = e0 + g; e < e1; e += 8) {
    unsigned u = sbuf[e];  // 8 lanes same addr: broadcast
    float nm = __half2float(__ushort_as_half((unsigned short)(u >> 16)));
    uint4 xr = ((const uint4*)(xht + (size_t)(u & 0xFFFFu) * 16))[cq];
    const __half2* hp = (const __half2*)&xr;
    float2 f0 = __half22float2(hp[0]);
    float2 f1 = __half22float2(hp[1]);
    float2 f2 = __half22float2(hp[2]);
    float2 f3 = __half22float2(hp[3]);
    v0 += nm * f0.x; v1 += nm * f0.y;
    v2 += nm * f1.x; v3 += nm * f1.y;
    v4 += nm * f2.x; v5 += nm * f2.y;
    v6 += nm * f3.x; v7 += nm * f3.y;
  }
  // reduce over the 8 edge groups (lane bits 2,3,4 — stays in node half/oct)
#pragma unroll
  for (int m = 4; m <= 16; m <<= 1) {
    v0 += __shfl_xor(v0, m); v1 += __shfl_xor(v1, m);
    v2 += __shfl_xor(v2, m); v3 += __shfl_xor(v3, m);
    v4 += __shfl_xor(v4, m); v5 += __shfl_xor(v5, m);
    v6 += __shfl_xor(v6, m); v7 += __shfl_xor(v7, m);
  }
  if (g == 0) {  // 4 lanes per node x 8 ch = all 32 channels
    float dv = dinv[n];
    const float4* xr4 = (const float4*)(xt + (size_t)n * IN_C);
    float4 xs0 = xr4[cq * 2];      // fp32 self-loop, ch cq*8 .. cq*8+3
    float4 xs1 = xr4[cq * 2 + 1];  // ch cq*8+4 .. cq*8+7
    __half2 o[4];
    o[0] = __floats2half2_rn(dv * (v0 + dv * xs0.x), dv * (v1 + dv * xs0.y));
    o[1] = __floats2half2_rn(dv * (v2 + dv * xs0.z), dv * (v3 + dv * xs0.w));
    o[2] = __floats2half2_rn(dv * (v4 + dv * xs1.x), dv * (v5 + dv * xs1.y));
    o[3] = __floats2half2_rn(dv * (v6 + dv * xs1.z), dv * (v7 + dv * xs1.w));
    __half2* yp = yG + ((size_t)tl * NN + n) * 16 + cq * 4;
    *(uint4*)yp = *(const uint4*)o;  // 16B store; 4 lanes fill the 64B row
  }
}

// Pass B2: MFMA gate (proven R17). P[64x64] = Y[64x32] @ M[32x64] per
// (64-node tile, t) via 16x16x32_f16; B-frags prepacked, loaded once.
// Grid x = GBLK4 = 782 (R22 bug: NN/64 = 781 dropped the 16-node tail);
// tail block clamps its A-row read and guards its writes.
__global__ __launch_bounds__(256) void gate_acc_kernel(
    const __half2* __restrict__ yG, const _Float16* __restrict__ B16,
    const float* __restrict__ Bz, const float* __restrict__ Bh,
    float* __restrict__ acc, int c) {
  int t = threadIdx.x;
  int w = t >> 6;
  int lane = t & 63;
  int nb = blockIdx.x * 64;
  int t0 = blockIdx.y * GT;
  int te = min(t0 + GT, c);

  half8_t bf[8];
#pragma unroll
  for (int q = 0; q < 8; ++q)
    bf[q] = *(const half8_t*)(B16 + ((size_t)q * 64 + lane) * 8);
  float bzv[4], bhv[4];
#pragma unroll
  for (int cc = 0; cc < 4; ++cc) {
    bzv[cc] = Bz[cc * 16 + (lane & 15)];
    bhv[cc] = Bh[cc * 16 + (lane & 15)];
  }
  float accr[16];
#pragma unroll
  for (int k = 0; k < 16; ++k) accr[k] = 0.f;

  const _Float16* yF = (const _Float16*)yG;
  int arow = nb + w * 16 + (lane & 15);      // A row this lane loads
  if (arow >= NN) arow = NN - 1;             // tail clamp (results discarded)
  int koff = (lane >> 4) * 8;                // k-offset within the row

  for (int tl = t0; tl < te; ++tl) {
    half8_t a = *(const half8_t*)(yF + ((size_t)tl * NN + arow) * 32 + koff);
    f32x4_t dz0 = {0.f, 0.f, 0.f, 0.f};
    f32x4_t dz[4], dh[4];
#pragma unroll
    for (int cc = 0; cc < 4; ++cc) {
      dz[cc] = __builtin_amdgcn_mfma_f32_16x16x32_f16(a, bf[cc], dz0, 0, 0, 0);
      dh[cc] = __builtin_amdgcn_mfma_f32_16x16x32_f16(a, bf[4 + cc], dz0, 0, 0, 0);
    }
#pragma unroll
    for (int cc = 0; cc < 4; ++cc) {
#pragma unroll
      for (int r = 0; r < 4; ++r) {
        float za = dz[cc][r] + bzv[cc];
        float ha = dh[cc][r] + bhv[cc];
        float z = 1.0f / (1.0f + __expf(-za));
        float th = 1.0f - 2.0f / (__expf(2.f * ha) + 1.0f);
        accr[cc * 4 + r] += (1.0f - z) * th;
      }
    }
  }
#pragma unroll
  for (int cc = 0; cc < 4; ++cc) {
#pragma unroll
    for (int r = 0; r < 4; ++r) {
      int n = nb + w * 16 + (lane >> 4) * 4 + r;
      int j = cc * 16 + (lane & 15);
      if (n < NN) atomicAdd(&acc[(size_t)n * HID + j], accr[cc * 4 + r]);
    }
  }
}

// out[n][o] = (acc[n]/T) . W_out[:,o] + b_out[o]
__global__ __launch_bounds__(256) void out_kernel(const float* __restrict__ acc,
                                                  const float* __restrict__ W_out,
                                                  const float* __restrict__ b_out,
                                                  float* __restrict__ out) {
  __shared__ float sW[HID * OUT_C], sB[OUT_C];
  for (int i = threadIdx.x; i < HID * OUT_C; i += 256) sW[i] = W_out[i];
  if (threadIdx.x < OUT_C) sB[threadIdx.x] = b_out[threadIdx.x];
  __syncthreads();
  unsigned tid = blockIdx.x * 256u + threadIdx.x;
  unsigned n = tid >> 5;
  int o = tid & 31;
  if (n >= NN) return;
  const float* ar = acc + (size_t)n * HID;
  float v = 0.f;
#pragma unroll
  for (int k = 0; k < HID; ++k) v += ar[k] * sW[k * OUT_C + o];
  out[(size_t)n * OUT_C + o] = v * (1.0f / (float)TT) + sB[o];
}

static inline char* alignp(char* p, size_t a) {
  return (char*)(((size_t)p + a - 1) & ~(a - 1));
}

extern "C" void kernel_launch(void* const* d_in, const int* in_sizes, int n_in,
                              void* d_out, int out_size, void* d_ws, size_t ws_size,
                              hipStream_t stream) {
  const float* x     = (const float*)d_in[0];  // [T,N,32]
  const int*   ei    = (const int*)d_in[1];    // [T,2,E]
  const float* ew    = (const float*)d_in[2];  // [T,E]
  const float* Wz    = (const float*)d_in[3];
  const float* bz    = (const float*)d_in[4];
  // d_in[5..6] (Wr,br) dead: H==0 so R unused
  const float* Wh    = (const float*)d_in[7];
  const float* bh    = (const float*)d_in[8];
  const float* Lz_w  = (const float*)d_in[9];
  const float* Lz_b  = (const float*)d_in[10];
  // d_in[11..12] (Lr) dead
  const float* Lh_w  = (const float*)d_in[13];
  const float* Lh_b  = (const float*)d_in[14];
  const float* W_out = (const float*)d_in[15];
  const float* b_out = (const float*)d_in[16];
  float* out = (float*)d_out;

  // per-t sizes (bytes)
  const size_t pcB    = (size_t)NN * 4;
  const size_t curB   = (size_t)NN * 4;
  const size_t noffB  = (size_t)(NN + 1) * 4;
  const size_t dinvB  = (size_t)NN * 4;
  const size_t bsumB  = (size_t)NBLK2 * 4;
  const size_t sbufB  = (size_t)EE * 4;            // 3.2 MB
  const size_t yB     = (size_t)NN * 16 * 4;       // 3.2 MB
  const size_t perT   = pcB + curB + noffB + dinvB + bsumB + sbufB + yB;  // ~7.2 MB
  const size_t xhB    = XPAIRS * 4;                // 38.4 MB
  const size_t fixedB = 4 * ((size_t)2 * IN_C * HID + 2 * HID)
                      + 8192 + (size_t)NN * HID * 4 + xhB + 4096;  // ~51.3 MB

  int nt = 12;
  if (ws_size < fixedB + 12 * perT) {
    nt = (int)((ws_size - fixedB) / perT);
    if (nt < 1) nt = 1;
    if (nt > 12) nt = 12;
  }

  char* p = (char*)d_ws;
  unsigned* pc = (unsigned*)p;      p += pcB * nt;
  int* cursor = (int*)p;            p += curB * nt;
  int* noffG  = (int*)p;            p += noffB * nt;
  float* dinv = (float*)p;          p += dinvB * nt;
  int* bsum   = (int*)p;            p += bsumB * nt;
  unsigned* sbufG = (unsigned*)p;   p += sbufB * nt;
  p = alignp(p, 16);
  __half2* yG = (__half2*)p;        p += yB * nt;
  _Float16* B16 = (_Float16*)p;     p += 8192;
  float* Mz = (float*)p;
  float* Mh = Mz + IN_C * HID;
  float* Bz = Mh + IN_C * HID;
  float* Bh = Bz + HID;
  float* acc = Bh + HID;  // [N,64]
  p = alignp((char*)(acc + (size_t)NN * HID), 256);
  __half2* xh = (__half2*)p;

  prep_kernel<<<dim3(IN_C + 1, 2), 64, 0, stream>>>(Wz, bz, Lz_w, Lz_b, Wh, bh,
                                                    Lh_w, Lh_b, Mz, Bz, Mh, Bh);
  prep_b16_kernel<<<dim3(4, 2), 64, 0, stream>>>(Mz, Mh, B16);
  xconv_kernel<<<(unsigned)((XPAIRS + 255) / 256), 256, 0, stream>>>(x, xh);
  hipMemsetAsync(acc, 0, (size_t)NN * HID * sizeof(float), stream);

  for (int tb = 0; tb < TT; tb += nt) {
    int c = (TT - tb < nt) ? (TT - tb) : nt;
    hipMemsetAsync(pc, 0, pcB * c, stream);
    hist_kernel<<<dim3(EBLK3, c), 256, 0, stream>>>(ei, ew, pc, tb);
    partial_kernel<<<dim3(NBLK2, c), 256, 0, stream>>>(pc, bsum);
    offs_kernel<<<dim3(NBLK2, c), 256, 0, stream>>>(bsum, pc, cursor, noffG, dinv);
    place_kernel<<<dim3(EBLK3, c), 256, 0, stream>>>(ei, ew, dinv, cursor,
                                                     sbufG, tb);
    gather_y_kernel<<<dim3(NN / 8, c), 256, 0, stream>>>(x, xh, dinv, noffG,
                                                         sbufG, yG, tb);
    gate_acc_kernel<<<dim3(GBLK4, (c + GT - 1) / GT), 256, 0, stream>>>(
        yG, B16, Bz, Bh, acc, c);
  }

  out_kernel<<<(NN * OUT_C + 255) / 256, 256, 0, stream>>>(acc, W_out, b_out, out);
}

// Round 24
// 642.923 us; speedup vs baseline: 1.7415x; 1.7415x over previous
//
#include <hip/hip_runtime.h>
#include <hip/hip_fp16.h>

#define NN 50000
#define TT 12
#define EE 800000
#define IN_C 32
#define HID 64
#define OUT_C 32
#define BSZ 64                        // nodes per bucket
#define NB ((NN + BSZ - 1) / BSZ)     // 782
#define CAP 1600                      // slots per (t,bucket); mean 1024
#define EPB 16384                     // edges per bin block
#define ABLK ((EE + EPB - 1) / EPB)   // 49
#define GT 4                          // timesteps per gate block
#define XPAIRS ((size_t)TT * NN * 16) // half2 elements in x

typedef _Float16 half8_t __attribute__((ext_vector_type(8)));
typedef float f32x4_t __attribute__((ext_vector_type(4)));

// ---------------- precompute folded gate matrices ----------------
// Mz = Wz @ Lz_w[:64] (32x64), Bz = bz @ Lz_w[:64] + Lz_b (64); same for h.
__global__ __launch_bounds__(64) void prep_kernel(
    const float* __restrict__ Wz, const float* __restrict__ bz,
    const float* __restrict__ Lzw, const float* __restrict__ Lzb,
    const float* __restrict__ Wh, const float* __restrict__ bh,
    const float* __restrict__ Lhw, const float* __restrict__ Lhb,
    float* __restrict__ Mz, float* __restrict__ Bz,
    float* __restrict__ Mh, float* __restrict__ Bh) {
  const int j = threadIdx.x;
  const int i = blockIdx.x;
  const int h = blockIdx.y;
  const float* W  = h ? Wh  : Wz;
  const float* b  = h ? bh  : bz;
  const float* L  = h ? Lhw : Lzw;
  const float* Lb = h ? Lhb : Lzb;
  float* M = h ? Mh : Mz;
  float* B = h ? Bh : Bz;
  if (i < IN_C) {
    float v = 0.f;
    for (int k = 0; k < HID; ++k) v += W[i * HID + k] * L[k * HID + j];
    M[i * HID + j] = v;
  } else {
    float v = Lb[j];
    for (int k = 0; k < HID; ++k) v += b[k] * L[k * HID + j];
    B[j] = v;
  }
}

// pack M into MFMA B-operand fp16 layout: B16[(g*4+cc)*64 + lane][i] =
// M_g[k = 8*(lane>>4)+i][col = cc*16 + (lane&15)]
__global__ __launch_bounds__(64) void prep_b16_kernel(
    const float* __restrict__ Mz, const float* __restrict__ Mh,
    _Float16* __restrict__ B16) {
  int l = threadIdx.x;
  int cc = blockIdx.x;  // coltile 0..3
  int g = blockIdx.y;   // 0=z, 1=h
  const float* M = g ? Mh : Mz;
#pragma unroll
  for (int i = 0; i < 8; ++i) {
    int k = (l >> 4) * 8 + i;
    int col = cc * 16 + (l & 15);
    B16[(((size_t)g * 4 + cc) * 64 + l) * 8 + i] = (_Float16)M[k * HID + col];
  }
}

// x [T,N,32] fp32 -> fp16 pairs
__global__ __launch_bounds__(256) void xconv_kernel(const float* __restrict__ x,
                                                    __half2* __restrict__ xh) {
  size_t i = (size_t)blockIdx.x * 256 + threadIdx.x;
  if (i < XPAIRS) {
    float2 f = ((const float2*)x)[i];
    xh[i] = __floats2half2_rn(f.x, f.y);
  }
}

// Pass A: coarse-bucket multisplit (proven R8-R21). Bucketing bounds write
// amp by confining each line's writers to one block (R23's direct scatter
// had 8-XCD line ping-pong: 17x amp).
__global__ __launch_bounds__(256) void bin_kernel(const int* __restrict__ ei,
                                                  const float* __restrict__ ew,
                                                  int* __restrict__ cursorA,
                                                  unsigned long long* __restrict__ binA,
                                                  int tbase) {
  __shared__ int hist[NB];
  __shared__ int rnk[NB];
  int tl = blockIdx.y;
  const int* src = ei + (size_t)(tbase + tl) * 2 * EE;
  const int* dst = src + EE;
  const float* w = ew + (size_t)(tbase + tl) * EE;
  int* cursor = cursorA + (size_t)tl * NB;
  unsigned long long* bin = binA + (size_t)tl * NB * CAP;
  int t = threadIdx.x;
  for (int i = t; i < NB; i += 256) { hist[i] = 0; rnk[i] = 0; }
  __syncthreads();
  int e0 = blockIdx.x * EPB;
#pragma unroll
  for (int i = 0; i < EPB / 256; ++i) {
    int e = e0 + i * 256 + t;
    if (e < EE) atomicAdd(&hist[dst[e] >> 6], 1);
  }
  __syncthreads();
  for (int b = t; b < NB; b += 256)
    hist[b] = atomicAdd(&cursor[b], hist[b]);  // hist becomes this block's base
  __syncthreads();
#pragma unroll
  for (int i = 0; i < EPB / 256; ++i) {
    int e = e0 + i * 256 + t;
    if (e < EE) {
      int d = dst[e], s = src[e];
      int b = d >> 6;
      unsigned short hw = __half_as_ushort(__float2half_rn(w[e]));
      int pos = hist[b] + atomicAdd(&rnk[b], 1);
      if (pos < CAP)
        bin[(size_t)b * CAP + pos] =
            (unsigned long long)((unsigned)s | ((unsigned)(d & 63) << 16)) |
            ((unsigned long long)hw << 32);
    }
  }
}

// per (bucket,t): deg = 1 + sum w over bucket entries, dinv = rsqrt(deg)
__global__ __launch_bounds__(256) void deg_kernel(const int* __restrict__ cursorA,
                                                  const unsigned long long* __restrict__ binA,
                                                  float* __restrict__ dinvA) {
  __shared__ float wsum[BSZ];
  int tl = blockIdx.y, b = blockIdx.x;
  int t = threadIdx.x;
  if (t < BSZ) wsum[t] = 0.f;
  __syncthreads();
  int cnt = min(cursorA[(size_t)tl * NB + b], CAP);
  const unsigned long long* bin = binA + ((size_t)tl * NB + b) * CAP;
  for (int i = t; i < cnt; i += 256) {
    unsigned long long u = bin[i];
    int dl = (int)((u >> 16) & 63u);
    float wv = __half2float(__ushort_as_half((unsigned short)(u >> 32)));
    atomicAdd(&wsum[dl], wv);
  }
  __syncthreads();
  int n = b * BSZ + t;
  if (t < BSZ && n < NN) dinvA[(size_t)tl * NN + n] = rsqrtf(1.0f + wsum[t]);
}

// exclusive scan of clamped bucket counts -> bucket bases (per t)
__global__ __launch_bounds__(1024) void bscan_kernel(const int* __restrict__ cursorA,
                                                     int* __restrict__ bbaseA) {
  __shared__ int s[1024];
  int tl = blockIdx.x, t = threadIdx.x;
  int v = (t < NB) ? min(cursorA[(size_t)tl * NB + t], CAP) : 0;
  s[t] = v;
  __syncthreads();
  for (int o = 1; o < 1024; o <<= 1) {
    int u = (t >= o) ? s[t - o] : 0;
    __syncthreads();
    s[t] += u;
    __syncthreads();
  }
  if (t < NB) bbaseA[(size_t)tl * NB + t] = s[t] - v;  // exclusive
}

// per (bucket,t): counting-sort bucket entries by dst&63 into global CSR
// sbufG {src16 | fp16(w*dinv[src])<<16}; write noffG per node.
__global__ __launch_bounds__(256) void sort_kernel(
    const int* __restrict__ cursorA, const int* __restrict__ bbaseA,
    const unsigned long long* __restrict__ binA, const float* __restrict__ dinvA,
    unsigned* __restrict__ sbufG, int* __restrict__ noffG) {
  __shared__ int hist[BSZ + 1];
  __shared__ int plc[BSZ];
  int tl = blockIdx.y, b = blockIdx.x;
  int t = threadIdx.x;
  if (t < BSZ + 1) hist[t] = 0;
  __syncthreads();
  int cnt = min(cursorA[(size_t)tl * NB + b], CAP);
  int base = bbaseA[(size_t)tl * NB + b];
  const unsigned long long* bin = binA + ((size_t)tl * NB + b) * CAP;
  const float* dinv = dinvA + (size_t)tl * NN;
  unsigned* sbuf = sbufG + (size_t)tl * EE;
  int* noff = noffG + (size_t)tl * (NN + 1);
  for (int e = t; e < cnt; e += 256)
    atomicAdd(&hist[(int)((bin[e] >> 16) & 63u)], 1);
  __syncthreads();
  if (t == 0) {
    int run = 0;
#pragma unroll
    for (int i = 0; i < BSZ; ++i) {
      int c = hist[i];
      hist[i] = run;
      plc[i] = run;
      run += c;
    }
    hist[BSZ] = run;
    if (b == NB - 1) noff[NN] = base + run;
  }
  __syncthreads();
  {
    int n = b * BSZ + t;
    if (t < BSZ && n < NN) noff[n] = base + hist[t];
  }
  for (int e = t; e < cnt; e += 256) {
    unsigned long long u = bin[e];
    int s = (int)(u & 0xFFFFu);
    int dl = (int)((u >> 16) & 63u);
    float nm = __half2float(__ushort_as_half((unsigned short)(u >> 32))) * dinv[s];
    int pos = base + atomicAdd(&plc[dl], 1);
    sbuf[pos] = (unsigned)s | ((unsigned)__half_as_ushort(__float2half_rn(nm)) << 16);
  }
}

// Pass B1: pure gather, NO LDS / NO barriers; t-major grid keeps xh_t
// L2-resident (proven R13/R21). lane = {node-half, 8 edge-groups, 4
// channel-octs}; per-edge uint4 row reads -> 16 row-loads in flight/wave.
__global__ __launch_bounds__(256) void gather_y_kernel(
    const float* __restrict__ x, const __half2* __restrict__ xh,
    const float* __restrict__ dinvA, const int* __restrict__ noffG,
    const unsigned* __restrict__ sbufG, __half2* __restrict__ yG, int tbase) {
  int t = threadIdx.x;
  int w = t >> 6;            // wave 0..3
  int lane = t & 63;
  int h2 = lane >> 5;        // node half 0/1
  int g = (lane >> 2) & 7;   // edge group 0..7
  int cq = lane & 3;         // channel oct 0..3 (8 fp16 ch = uint4)
  int tl = blockIdx.y;
  int n = blockIdx.x * 8 + w * 2 + h2;  // NN % 8 == 0, no tail

  const float* dinv = dinvA + (size_t)tl * NN;
  const int* noff = noffG + (size_t)tl * (NN + 1);
  const unsigned* sbuf = sbufG + (size_t)tl * EE;
  const __half2* xht = xh + (size_t)(tbase + tl) * NN * 16;
  const float* xt = x + (size_t)(tbase + tl) * NN * IN_C;

  int e0 = noff[n], e1 = noff[n + 1];
  float v0 = 0.f, v1 = 0.f, v2 = 0.f, v3 = 0.f;
  float v4 = 0.f, v5 = 0.f, v6 = 0.f, v7 = 0.f;
  for (int e = e0 + g; e < e1; e += 8) {
    unsigned u = sbuf[e];  // 8 lanes same addr: broadcast
    float nm = __half2float(__ushort_as_half((unsigned short)(u >> 16)));
    uint4 xr = ((const uint4*)(xht + (size_t)(u & 0xFFFFu) * 16))[cq];
    const __half2* hp = (const __half2*)&xr;
    float2 f0 = __half22float2(hp[0]);
    float2 f1 = __half22float2(hp[1]);
    float2 f2 = __half22float2(hp[2]);
    float2 f3 = __half22float2(hp[3]);
    v0 += nm * f0.x; v1 += nm * f0.y;
    v2 += nm * f1.x; v3 += nm * f1.y;
    v4 += nm * f2.x; v5 += nm * f2.y;
    v6 += nm * f3.x; v7 += nm * f3.y;
  }
  // reduce over the 8 edge groups (lane bits 2,3,4 — stays in node half/oct)
#pragma unroll
  for (int m = 4; m <= 16; m <<= 1) {
    v0 += __shfl_xor(v0, m); v1 += __shfl_xor(v1, m);
    v2 += __shfl_xor(v2, m); v3 += __shfl_xor(v3, m);
    v4 += __shfl_xor(v4, m); v5 += __shfl_xor(v5, m);
    v6 += __shfl_xor(v6, m); v7 += __shfl_xor(v7, m);
  }
  if (g == 0) {  // 4 lanes per node x 8 ch = all 32 channels
    float dv = dinv[n];
    const float4* xr4 = (const float4*)(xt + (size_t)n * IN_C);
    float4 xs0 = xr4[cq * 2];      // fp32 self-loop, ch cq*8 .. cq*8+3
    float4 xs1 = xr4[cq * 2 + 1];  // ch cq*8+4 .. cq*8+7
    __half2 o[4];
    o[0] = __floats2half2_rn(dv * (v0 + dv * xs0.x), dv * (v1 + dv * xs0.y));
    o[1] = __floats2half2_rn(dv * (v2 + dv * xs0.z), dv * (v3 + dv * xs0.w));
    o[2] = __floats2half2_rn(dv * (v4 + dv * xs1.x), dv * (v5 + dv * xs1.y));
    o[3] = __floats2half2_rn(dv * (v6 + dv * xs1.z), dv * (v7 + dv * xs1.w));
    __half2* yp = yG + ((size_t)tl * NN + n) * 16 + cq * 4;
    *(uint4*)yp = *(const uint4*)o;  // 16B store; 4 lanes fill the 64B row
  }
}

// Pass B2: MFMA gate (proven R17). P[64x64] = Y[64x32] @ M[32x64] per
// (bucket,t) via 16x16x32_f16; B-frags prepacked, loaded once.
__global__ __launch_bounds__(256) void gate_acc_kernel(
    const __half2* __restrict__ yG, const _Float16* __restrict__ B16,
    const float* __restrict__ Bz, const float* __restrict__ Bh,
    float* __restrict__ acc, int c) {
  int t = threadIdx.x;
  int w = t >> 6;
  int lane = t & 63;
  int nb = blockIdx.x * BSZ;
  int t0 = blockIdx.y * GT;
  int te = min(t0 + GT, c);

  half8_t bf[8];
#pragma unroll
  for (int q = 0; q < 8; ++q)
    bf[q] = *(const half8_t*)(B16 + ((size_t)q * 64 + lane) * 8);
  float bzv[4], bhv[4];
#pragma unroll
  for (int cc = 0; cc < 4; ++cc) {
    bzv[cc] = Bz[cc * 16 + (lane & 15)];
    bhv[cc] = Bh[cc * 16 + (lane & 15)];
  }
  float accr[16];
#pragma unroll
  for (int k = 0; k < 16; ++k) accr[k] = 0.f;

  const _Float16* yF = (const _Float16*)yG;
  int arow = nb + w * 16 + (lane & 15);   // A row this lane loads
  int koff = (lane >> 4) * 8;             // k-offset within the row

  for (int tl = t0; tl < te; ++tl) {
    half8_t a = *(const half8_t*)(yF + ((size_t)tl * NN + arow) * 32 + koff);
    f32x4_t dz0 = {0.f, 0.f, 0.f, 0.f};
    f32x4_t dz[4], dh[4];
#pragma unroll
    for (int cc = 0; cc < 4; ++cc) {
      dz[cc] = __builtin_amdgcn_mfma_f32_16x16x32_f16(a, bf[cc], dz0, 0, 0, 0);
      dh[cc] = __builtin_amdgcn_mfma_f32_16x16x32_f16(a, bf[4 + cc], dz0, 0, 0, 0);
    }
#pragma unroll
    for (int cc = 0; cc < 4; ++cc) {
#pragma unroll
      for (int r = 0; r < 4; ++r) {
        float za = dz[cc][r] + bzv[cc];
        float ha = dh[cc][r] + bhv[cc];
        float z = 1.0f / (1.0f + __expf(-za));
        float th = 1.0f - 2.0f / (__expf(2.f * ha) + 1.0f);
        accr[cc * 4 + r] += (1.0f - z) * th;
      }
    }
  }
#pragma unroll
  for (int cc = 0; cc < 4; ++cc) {
#pragma unroll
    for (int r = 0; r < 4; ++r) {
      int n = nb + w * 16 + (lane >> 4) * 4 + r;
      int j = cc * 16 + (lane & 15);
      if (n < NN) atomicAdd(&acc[(size_t)n * HID + j], accr[cc * 4 + r]);
    }
  }
}

// out[n][o] = (acc[n]/T) . W_out[:,o] + b_out[o]
__global__ __launch_bounds__(256) void out_kernel(const float* __restrict__ acc,
                                                  const float* __restrict__ W_out,
                                                  const float* __restrict__ b_out,
                                                  float* __restrict__ out) {
  __shared__ float sW[HID * OUT_C], sB[OUT_C];
  for (int i = threadIdx.x; i < HID * OUT_C; i += 256) sW[i] = W_out[i];
  if (threadIdx.x < OUT_C) sB[threadIdx.x] = b_out[threadIdx.x];
  __syncthreads();
  unsigned tid = blockIdx.x * 256u + threadIdx.x;
  unsigned n = tid >> 5;
  int o = tid & 31;
  if (n >= NN) return;
  const float* ar = acc + (size_t)n * HID;
  float v = 0.f;
#pragma unroll
  for (int k = 0; k < HID; ++k) v += ar[k] * sW[k * OUT_C + o];
  out[(size_t)n * OUT_C + o] = v * (1.0f / (float)TT) + sB[o];
}

static inline char* alignp(char* p, size_t a) {
  return (char*)(((size_t)p + a - 1) & ~(a - 1));
}

extern "C" void kernel_launch(void* const* d_in, const int* in_sizes, int n_in,
                              void* d_out, int out_size, void* d_ws, size_t ws_size,
                              hipStream_t stream) {
  const float* x     = (const float*)d_in[0];  // [T,N,32]
  const int*   ei    = (const int*)d_in[1];    // [T,2,E]
  const float* ew    = (const float*)d_in[2];  // [T,E]
  const float* Wz    = (const float*)d_in[3];
  const float* bz    = (const float*)d_in[4];
  // d_in[5..6] (Wr,br) dead: H==0 so R unused
  const float* Wh    = (const float*)d_in[7];
  const float* bh    = (const float*)d_in[8];
  const float* Lz_w  = (const float*)d_in[9];
  const float* Lz_b  = (const float*)d_in[10];
  // d_in[11..12] (Lr) dead
  const float* Lh_w  = (const float*)d_in[13];
  const float* Lh_b  = (const float*)d_in[14];
  const float* W_out = (const float*)d_in[15];
  const float* b_out = (const float*)d_in[16];
  float* out = (float*)d_out;

  // per-t sizes (bytes)
  const size_t binB   = (size_t)NB * CAP * 8;     // 10.0 MB (y aliases this)
  const size_t curB   = (size_t)NB * 4;
  const size_t bbB    = (size_t)NB * 4;
  const size_t dinvB  = (size_t)NN * 4;
  const size_t noffB  = (size_t)(NN + 1) * 4;
  const size_t sbufB  = (size_t)EE * 4;           // 3.2 MB
  const size_t perT   = binB + curB + bbB + dinvB + noffB + sbufB;  // ~13.6 MB
  const size_t xhB    = XPAIRS * 4;               // 38.4 MB
  const size_t fixedB = 4 * ((size_t)2 * IN_C * HID + 2 * HID)
                      + 8192 + (size_t)NN * HID * 4 + xhB + 4096;  // ~51.3 MB

  int nt = 12;
  if (ws_size < fixedB + 12 * perT) {
    nt = (int)((ws_size - fixedB) / perT);
    if (nt < 1) nt = 1;
    if (nt > 12) nt = 12;
  }

  char* p = (char*)d_ws;
  unsigned long long* bin = (unsigned long long*)p;  // 8-aligned at base
  p += binB * nt;
  int* cursor = (int*)p;   p += curB * nt;
  int* bbase  = (int*)p;   p += bbB * nt;
  float* dinv = (float*)p; p += dinvB * nt;
  int* noffG  = (int*)p;   p += noffB * nt;
  unsigned* sbufG = (unsigned*)p; p += sbufB * nt;
  p = alignp(p, 16);
  _Float16* B16 = (_Float16*)p; p += 8192;  // 4096 fp16 MFMA B-frags
  float* Mz = (float*)p;
  float* Mh = Mz + IN_C * HID;
  float* Bz = Mh + IN_C * HID;
  float* Bh = Bz + HID;
  float* acc = Bh + HID;  // [N,64]
  p = alignp((char*)(acc + (size_t)NN * HID), 256);
  __half2* xh = (__half2*)p;
  // y [nt,N,32] fp16 aliases the bin region: bin is dead after sort_kernel,
  // and stream order guarantees sort (reads bin) < gather_y (writes y) <
  // gate_acc (reads y) < next chunk's bin_kernel (rewrites bin).
  __half2* yG = (__half2*)bin;

  prep_kernel<<<dim3(IN_C + 1, 2), 64, 0, stream>>>(Wz, bz, Lz_w, Lz_b, Wh, bh,
                                                    Lh_w, Lh_b, Mz, Bz, Mh, Bh);
  prep_b16_kernel<<<dim3(4, 2), 64, 0, stream>>>(Mz, Mh, B16);
  xconv_kernel<<<(unsigned)((XPAIRS + 255) / 256), 256, 0, stream>>>(x, xh);
  hipMemsetAsync(acc, 0, (size_t)NN * HID * sizeof(float), stream);

  for (int tb = 0; tb < TT; tb += nt) {
    int c = (TT - tb < nt) ? (TT - tb) : nt;
    hipMemsetAsync(cursor, 0, curB * c, stream);
    bin_kernel<<<dim3(ABLK, c), 256, 0, stream>>>(ei, ew, cursor, bin, tb);
    deg_kernel<<<dim3(NB, c), 256, 0, stream>>>(cursor, bin, dinv);
    bscan_kernel<<<c, 1024, 0, stream>>>(cursor, bbase);
    sort_kernel<<<dim3(NB, c), 256, 0, stream>>>(cursor, bbase, bin, dinv,
                                                 sbufG, noffG);
    gather_y_kernel<<<dim3(NN / 8, c), 256, 0, stream>>>(x, xh, dinv, noffG,
                                                         sbufG, yG, tb);
    gate_acc_kernel<<<dim3(NB, (c + GT - 1) / GT), 256, 0, stream>>>(
        yG, B16, Bz, Bh, acc, c);
  }

  out_kernel<<<(NN * OUT_C + 255) / 256, 256, 0, stream>>>(acc, W_out, b_out, out);
}